// Round 12
// baseline (374.463 us; speedup 1.0000x reference)
//
#include <hip/hip_runtime.h>
#include <math.h>

#define BATCH 65536
#define XPER  576               // 24*24 floats per image
#define NBLK  1024              // == 4 blocks/CU * 256 CUs (co-resident by construction)
#define WPB   4                 // waves per block
#define IPR   8                 // images per wave-round
#define RPW   2                 // rounds per wave
// block covers WPB*IPR*RPW = 64 images

// ws layout: slots[NBLK][8] floats (32 KB, fully overwritten each launch),
// then {cnt, flag} u32 at byte offset NBLK*8*4 (zeroed by 8-byte memset node).

// ---------------------------------------------------------------- K1
// Direct-from-global pooling (R9/R11 structure) + fused BN via a proper
// grid barrier: plain slot stores, one release fetch_add per block to
// arrive, acquire-LOAD polling (no RMW storm — the R6 bug), phase-B slot
// reduction per block, z scaled in registers, single store.
__global__ __launch_bounds__(256, 4) void circuit_kernel(
        const float* __restrict__ x, const float* __restrict__ params,
        const float* __restrict__ gamma, const float* __restrict__ beta,
        float* __restrict__ out, float* __restrict__ ws) {
    __shared__ float sUr[16 * 20];     // U real, row r at r*20 (padded)
    __shared__ float sUi[16 * 20];     // U imag
    __shared__ float sg[48];           // 8 gates x {c,s,epr,epi,emr,emi}
    __shared__ float sv[WPB][IPR * 20];// per-wave pooled-v strips (padded)
    __shared__ float spart[8];
    __shared__ float red[256];         // phase-B reduction / coefs

    float* slots = ws;
    unsigned* cnt  = (unsigned*)(ws + NBLK * 8);
    unsigned* flag = cnt + 1;

    const int t    = threadIdx.x;
    const int wid  = t >> 6;           // wave id (0..3)
    const int lane = t & 63;
    const int e    = lane >> 3;        // image within round (0..7)
    const int q    = lane & 7;         // cell pair (covers cells 2q, 2q+1)
    const int pr   = q >> 1;           // cell row (0..3)
    const int P    = q & 1;            // pair column (0..1)

    if (t < 8) {
        spart[t] = 0.0f;
        float phi   = params[t * 3 + 0];
        float theta = params[t * 3 + 1];
        float omega = params[t * 3 + 2];
        float apo = 0.5f * (phi + omega), amo = 0.5f * (phi - omega);
        sg[t * 6 + 0] = cosf(0.5f * theta);
        sg[t * 6 + 1] = sinf(0.5f * theta);
        sg[t * 6 + 2] = cosf(apo);           // epr (ep = e^{-i(phi+omega)/2})
        sg[t * 6 + 3] = -sinf(apo);          // epi
        sg[t * 6 + 4] = cosf(amo);           // emr (em = e^{+i(phi-omega)/2})
        sg[t * 6 + 5] = sinf(amo);           // emi
    }
    __syncthreads();

    // ---- fold circuit into U (lane j owns column j of M; state' = M state)
    if (t < 16) {
        const int j = t;
        float Mr[16], Mi[16];
#pragma unroll
        for (int i = 0; i < 16; ++i) { Mr[i] = (i == j) ? 1.0f : 0.0f; Mi[i] = 0.0f; }
#pragma unroll
        for (int l = 0; l < 2; ++l) {
#pragma unroll
            for (int w = 0; w < 4; ++w) {
                const int g = l * 4 + w;
                float c   = sg[g * 6 + 0], s   = sg[g * 6 + 1];
                float epr = sg[g * 6 + 2], epi = sg[g * 6 + 3];
                float emr = sg[g * 6 + 4], emi = sg[g * 6 + 5];
                float m00r =  epr * c, m00i =  epi * c;
                float m01r = -emr * s, m01i = -emi * s;
                float m10r =  emr * s, m10i = -emi * s;
                float m11r =  epr * c, m11i = -epi * c;
                const int mask = 1 << (3 - w);
#pragma unroll
                for (int i = 0; i < 16; ++i) {
                    if (i & mask) continue;
                    int i1 = i | mask;
                    float r0 = Mr[i],  q0 = Mi[i];
                    float r1 = Mr[i1], q1 = Mi[i1];
                    Mr[i]  = m00r * r0 - m00i * q0 + m01r * r1 - m01i * q1;
                    Mi[i]  = m00r * q0 + m00i * r0 + m01r * q1 + m01i * r1;
                    Mr[i1] = m10r * r0 - m10i * q0 + m11r * r1 - m11i * q1;
                    Mi[i1] = m10r * q0 + m10i * r0 + m11r * q1 + m11i * r1;
                }
            }
            const int rr = (l % 3) + 1;
#pragma unroll
            for (int w = 0; w < 4; ++w) {
                int tq = (w + rr) & 3;
                int cb = 3 - w, tb = 3 - tq;
#pragma unroll
                for (int i = 0; i < 16; ++i) {
                    int pi = i ^ (((i >> cb) & 1) << tb);
                    if (pi > i) {
                        float tr = Mr[i]; Mr[i] = Mr[pi]; Mr[pi] = tr;
                        float ti = Mi[i]; Mi[i] = Mi[pi]; Mi[pi] = ti;
                    }
                }
            }
        }
#pragma unroll
        for (int i = 0; i < 16; ++i) {
            sUr[i * 20 + j] = Mr[i];
            sUi[i * 20 + j] = Mi[i];
        }
    }
    __syncthreads();

    // writer lane -> channel: z0@q=4, z1@q=2, z2@q=1, z3@q=0
    int c = -1;
    if      (q == 4) c = 0;
    else if (q == 2) c = 1;
    else if (q == 1) c = 2;
    else if (q == 0) c = 3;

    const int cbase = pr * 144 + P * 12;   // strip base within image (floats)
    float zv[RPW];
    float accz = 0.0f, accz2 = 0.0f;

#pragma unroll
    for (int rd = 0; rd < RPW; ++rd) {
        const size_t img = (size_t)blockIdx.x * 64 + (size_t)wid * (IPR * RPW)
                         + (size_t)rd * IPR + e;
        const float* ip = x + img * XPER + cbase;

        // ---- pool the 12x6 strip: 18 aligned float4 loads, two cell sums
        float L = 0.0f, R = 0.0f;
#pragma unroll
        for (int r = 0; r < 6; ++r) {
            float4 a = *(const float4*)(ip + r * 24);
            float4 b = *(const float4*)(ip + r * 24 + 4);
            float4 d = *(const float4*)(ip + r * 24 + 8);
            L += a.x + a.y + a.z + a.w + b.x + b.y;
            R += b.z + b.w + d.x + d.y + d.z + d.w;
        }
        float vL = L * (1.0f / 36.0f), vR = R * (1.0f / 36.0f);

        // ---- redistribute via per-wave padded strip (wave-private, DS
        // in-order per wave => no barrier)
        *(float2*)(&sv[wid][e * 20 + 2 * q]) = make_float2(vL, vR);

        // ---- matvec for state rows 2q, 2q+1; vv and U via b128 LDS reads
        float n2 = 0.0f, sr0 = 0.0f, si0 = 0.0f, sr1 = 0.0f, si1 = 0.0f;
#pragma unroll
        for (int m = 0; m < 4; ++m) {
            float4 v4 = *(const float4*)(&sv[wid][e * 20 + 4 * m]);
            float4 a0 = *(const float4*)(sUr + (2 * q) * 20 + 4 * m);
            float4 b0 = *(const float4*)(sUi + (2 * q) * 20 + 4 * m);
            float4 a1 = *(const float4*)(sUr + (2 * q + 1) * 20 + 4 * m);
            float4 b1 = *(const float4*)(sUi + (2 * q + 1) * 20 + 4 * m);
            n2  = fmaf(v4.x, v4.x, fmaf(v4.y, v4.y, fmaf(v4.z, v4.z, fmaf(v4.w, v4.w, n2))));
            sr0 = fmaf(a0.x, v4.x, fmaf(a0.y, v4.y, fmaf(a0.z, v4.z, fmaf(a0.w, v4.w, sr0))));
            si0 = fmaf(b0.x, v4.x, fmaf(b0.y, v4.y, fmaf(b0.z, v4.z, fmaf(b0.w, v4.w, si0))));
            sr1 = fmaf(a1.x, v4.x, fmaf(a1.y, v4.y, fmaf(a1.z, v4.z, fmaf(a1.w, v4.w, sr1))));
            si1 = fmaf(b1.x, v4.x, fmaf(b1.y, v4.y, fmaf(b1.z, v4.z, fmaf(b1.w, v4.w, si1))));
        }
        float inv = 1.0f / n2;
        float p0 = (sr0 * sr0 + si0 * si0) * inv;
        float p1 = (sr1 * sr1 + si1 * si1) * inv;

        // ---- WHT: bit0 in-register, bits 1..3 via 8-lane butterflies
        float u = p0 + p1, d = p0 - p1, o;
        o = __shfl_xor(u, 1); u = (q & 1) ? (o - u) : (u + o);
        o = __shfl_xor(u, 2); u = (q & 2) ? (o - u) : (u + o);
        o = __shfl_xor(u, 4); u = (q & 4) ? (o - u) : (u + o);
        d += __shfl_xor(d, 1);
        d += __shfl_xor(d, 2);
        d += __shfl_xor(d, 4);

        float z = (q == 0) ? d : u;
        zv[rd] = z;
        if (c >= 0) { accz += z; accz2 += z * z; }
    }

    // ---- per-block partials -> private slot (plain stores)
    if (c >= 0) {
        atomicAdd(&spart[c], accz);
        atomicAdd(&spart[4 + c], accz2);
    }
    __syncthreads();
    if (t < 8) slots[blockIdx.x * 8 + t] = spart[t];
    __threadfence();                       // release slot stores (agent scope)
    __syncthreads();

    // ---- grid barrier: one release RMW per block; ACQUIRE-LOAD polling
    if (t == 0) {
        unsigned old = __hip_atomic_fetch_add(cnt, 1u, __ATOMIC_ACQ_REL,
                                              __HIP_MEMORY_SCOPE_AGENT);
        if (old == NBLK - 1) {
            __hip_atomic_store(flag, 1u, __ATOMIC_RELEASE,
                               __HIP_MEMORY_SCOPE_AGENT);
        } else {
            while (__hip_atomic_load(flag, __ATOMIC_ACQUIRE,
                                     __HIP_MEMORY_SCOPE_AGENT) == 0u)
                __builtin_amdgcn_s_sleep(16);
        }
    }
    __syncthreads();
    __threadfence();                       // acquire: invalidate L1 for slot reads

    // ---- phase B: every block reduces the slot array (L2-resident)
    {
        const int ch = t & 7, g = t >> 3;  // g in 0..31
        float s = 0.0f;
#pragma unroll
        for (int k = 0; k < NBLK / 32; ++k)
            s += slots[(size_t)(g + 32 * k) * 8 + ch];
        red[t] = s;
    }
    __syncthreads();
#pragma unroll
    for (int stp = 128; stp >= 8; stp >>= 1) {
        if (t < stp) red[t] += red[t + stp];
        __syncthreads();
    }
    if (t < 4) {
        float mu  = red[t] * (1.0f / BATCH);
        float var = red[4 + t] * (1.0f / BATCH) - mu * mu;
        float a = gamma[t] * rsqrtf(var + 1e-5f);
        red[t]     = a;                    // reuse red[0..7] for coefs
        red[4 + t] = beta[t] - mu * a;
    }
    __syncthreads();

    // ---- apply BN to reg-resident z, pack to q==0, single store pass
    float A = (c >= 0) ? red[c] : 0.0f;
    float B = (c >= 0) ? red[4 + c] : 0.0f;
#pragma unroll
    for (int rd = 0; rd < RPW; ++rd) {
        const size_t img = (size_t)blockIdx.x * 64 + (size_t)wid * (IPR * RPW)
                         + (size_t)rd * IPR + e;
        float zn = fmaf(zv[rd], A, B);
        int gb = lane & ~7;
        float z0 = __shfl(zn, gb | 4);
        float z1 = __shfl(zn, gb | 2);
        float z2 = __shfl(zn, gb | 1);
        if (q == 0)
            ((float4*)out)[img] = make_float4(z0, z1, z2, zn);
    }
}

extern "C" void kernel_launch(void* const* d_in, const int* in_sizes, int n_in,
                              void* d_out, int out_size, void* d_ws, size_t ws_size,
                              hipStream_t stream) {
    const float* x      = (const float*)d_in[0];
    const float* params = (const float*)d_in[1];
    const float* gamma  = (const float*)d_in[2];
    const float* beta   = (const float*)d_in[3];
    float* out = (float*)d_out;
    float* ws  = (float*)d_ws;

    // zero only the barrier words (slots are fully overwritten pre-barrier)
    hipMemsetAsync((char*)d_ws + NBLK * 8 * sizeof(float), 0, 8, stream);
    hipLaunchKernelGGL(circuit_kernel, dim3(NBLK), dim3(256), 0, stream,
                       x, params, gamma, beta, out, ws);
}

// Round 13
// 36.031 us; speedup vs baseline: 10.3929x; 10.3929x over previous
//
#include <hip/hip_runtime.h>
#include <math.h>

#define BATCH 65536
#define XPER  576               // 24*24 floats per image
#define NBLK  1024
#define WPB   4                 // waves per block
#define RPW   2                 // rounds per wave
#define IPR   8                 // images per round per wave
// block covers WPB*RPW*IPR = 64 images

// ws layout: slots[NBLK][8] partial sums (fully overwritten each launch;
// no zeroing, no global atomics, no memset node).

// ---------------------------------------------------------------- K1
// Direct-from-global pooling (no LDS staging). Lane = (image e, cell-pair q).
// 18 aligned float4 loads cover the pair strip (12 cols x 6 rows); lane's
// pooled cells (2q, 2q+1) are exactly its two matvec state rows.
__global__ __launch_bounds__(256, 3) void circuit_kernel(
        const float* __restrict__ x, const float* __restrict__ params,
        float* __restrict__ out, float* __restrict__ slots) {
    __shared__ float sUr[16 * 20];     // U real, row r at r*20 (padded)
    __shared__ float sUi[16 * 20];     // U imag
    __shared__ float sg[48];           // 8 gates x {c,s,epr,epi,emr,emi}
    __shared__ float sv[WPB][IPR * 20];// per-wave pooled-v strips (padded)
    __shared__ float spart[8];

    const int t    = threadIdx.x;
    const int wid  = t >> 6;           // wave id (0..3)
    const int lane = t & 63;
    const int e    = lane >> 3;        // image within round (0..7)
    const int q    = lane & 7;         // cell pair (covers cells 2q, 2q+1)
    const int pr   = q >> 1;           // cell row (0..3)
    const int P    = q & 1;            // pair column (0..1)

    if (t < 8) {
        spart[t] = 0.0f;
        float phi   = params[t * 3 + 0];
        float theta = params[t * 3 + 1];
        float omega = params[t * 3 + 2];
        float apo = 0.5f * (phi + omega), amo = 0.5f * (phi - omega);
        sg[t * 6 + 0] = cosf(0.5f * theta);
        sg[t * 6 + 1] = sinf(0.5f * theta);
        sg[t * 6 + 2] = cosf(apo);           // epr (ep = e^{-i(phi+omega)/2})
        sg[t * 6 + 3] = -sinf(apo);          // epi
        sg[t * 6 + 4] = cosf(amo);           // emr (em = e^{+i(phi-omega)/2})
        sg[t * 6 + 5] = sinf(amo);           // emi
    }
    __syncthreads();

    // ---- fold circuit into U (lane j owns column j of M; state' = M state)
    if (t < 16) {
        const int j = t;
        float Mr[16], Mi[16];
#pragma unroll
        for (int i = 0; i < 16; ++i) { Mr[i] = (i == j) ? 1.0f : 0.0f; Mi[i] = 0.0f; }
#pragma unroll
        for (int l = 0; l < 2; ++l) {
#pragma unroll
            for (int w = 0; w < 4; ++w) {
                const int g = l * 4 + w;
                float c   = sg[g * 6 + 0], s   = sg[g * 6 + 1];
                float epr = sg[g * 6 + 2], epi = sg[g * 6 + 3];
                float emr = sg[g * 6 + 4], emi = sg[g * 6 + 5];
                float m00r =  epr * c, m00i =  epi * c;
                float m01r = -emr * s, m01i = -emi * s;
                float m10r =  emr * s, m10i = -emi * s;
                float m11r =  epr * c, m11i = -epi * c;
                const int mask = 1 << (3 - w);
#pragma unroll
                for (int i = 0; i < 16; ++i) {
                    if (i & mask) continue;
                    int i1 = i | mask;
                    float r0 = Mr[i],  q0 = Mi[i];
                    float r1 = Mr[i1], q1 = Mi[i1];
                    Mr[i]  = m00r * r0 - m00i * q0 + m01r * r1 - m01i * q1;
                    Mi[i]  = m00r * q0 + m00i * r0 + m01r * q1 + m01i * r1;
                    Mr[i1] = m10r * r0 - m10i * q0 + m11r * r1 - m11i * q1;
                    Mi[i1] = m10r * q0 + m10i * r0 + m11r * q1 + m11i * r1;
                }
            }
            const int rr = (l % 3) + 1;
#pragma unroll
            for (int w = 0; w < 4; ++w) {
                int tq = (w + rr) & 3;
                int cb = 3 - w, tb = 3 - tq;
#pragma unroll
                for (int i = 0; i < 16; ++i) {
                    int pi = i ^ (((i >> cb) & 1) << tb);
                    if (pi > i) {
                        float tr = Mr[i]; Mr[i] = Mr[pi]; Mr[pi] = tr;
                        float ti = Mi[i]; Mi[i] = Mi[pi]; Mi[pi] = ti;
                    }
                }
            }
        }
#pragma unroll
        for (int i = 0; i < 16; ++i) {
            sUr[i * 20 + j] = Mr[i];
            sUi[i * 20 + j] = Mi[i];
        }
    }
    __syncthreads();

    // ---- hoist this lane's two U rows (2q, 2q+1) into registers
    float u0r[16], u0i[16], u1r[16], u1i[16];
    {
        const float4* r0 = (const float4*)(sUr + (2 * q) * 20);
        const float4* r1 = (const float4*)(sUr + (2 * q + 1) * 20);
        const float4* i0 = (const float4*)(sUi + (2 * q) * 20);
        const float4* i1 = (const float4*)(sUi + (2 * q + 1) * 20);
#pragma unroll
        for (int m = 0; m < 4; ++m) {
            float4 a = r0[m], b = r1[m], cc = i0[m], d = i1[m];
            u0r[4*m+0]=a.x; u0r[4*m+1]=a.y; u0r[4*m+2]=a.z; u0r[4*m+3]=a.w;
            u1r[4*m+0]=b.x; u1r[4*m+1]=b.y; u1r[4*m+2]=b.z; u1r[4*m+3]=b.w;
            u0i[4*m+0]=cc.x; u0i[4*m+1]=cc.y; u0i[4*m+2]=cc.z; u0i[4*m+3]=cc.w;
            u1i[4*m+0]=d.x; u1i[4*m+1]=d.y; u1i[4*m+2]=d.z; u1i[4*m+3]=d.w;
        }
    }

    // writer lane -> channel: z0@q=4, z1@q=2, z2@q=1, z3@q=0
    int c = -1;
    if      (q == 4) c = 0;
    else if (q == 2) c = 1;
    else if (q == 1) c = 2;
    else if (q == 0) c = 3;

    const int cbase = pr * 144 + P * 12;   // strip base within image (floats)
    float accz = 0.0f, accz2 = 0.0f;

#pragma unroll
    for (int rd = 0; rd < RPW; ++rd) {
        const size_t img = (size_t)blockIdx.x * 64 + wid * 16 + rd * 8 + e;
        const float* ip = x + img * XPER + cbase;

        // ---- pool the 12x6 strip: 18 aligned float4 loads, two cell sums
        float L = 0.0f, R = 0.0f;
#pragma unroll
        for (int r = 0; r < 6; ++r) {
            float4 a = *(const float4*)(ip + r * 24);
            float4 b = *(const float4*)(ip + r * 24 + 4);
            float4 d = *(const float4*)(ip + r * 24 + 8);
            L += a.x + a.y + a.z + a.w + b.x + b.y;
            R += b.z + b.w + d.x + d.y + d.z + d.w;
        }
        float vL = L * (1.0f / 36.0f), vR = R * (1.0f / 36.0f);

        // ---- redistribute via per-wave padded strip (write b64, 4x b128
        // broadcast reads; wave-private + DS in-order => no barrier)
        *(float2*)(&sv[wid][e * 20 + 2 * q]) = make_float2(vL, vR);
        float vv[16];
        {
            const float4* vb = (const float4*)(&sv[wid][e * 20]);
#pragma unroll
            for (int m = 0; m < 4; ++m) {
                float4 a = vb[m];
                vv[4*m+0]=a.x; vv[4*m+1]=a.y; vv[4*m+2]=a.z; vv[4*m+3]=a.w;
            }
        }

        // ---- matvec for state rows 2q, 2q+1 (input state real)
        float n2 = 0.0f, sr0 = 0.0f, si0 = 0.0f, sr1 = 0.0f, si1 = 0.0f;
#pragma unroll
        for (int j = 0; j < 16; ++j) {
            float vj = vv[j];
            n2  = fmaf(vj, vj, n2);
            sr0 = fmaf(u0r[j], vj, sr0); si0 = fmaf(u0i[j], vj, si0);
            sr1 = fmaf(u1r[j], vj, sr1); si1 = fmaf(u1i[j], vj, si1);
        }
        float inv = 1.0f / n2;
        float p0 = (sr0 * sr0 + si0 * si0) * inv;
        float p1 = (sr1 * sr1 + si1 * si1) * inv;

        // ---- WHT: bit0 in-register, bits 1..3 via 8-lane butterflies
        float u = p0 + p1, d = p0 - p1, o;
        o = __shfl_xor(u, 1); u = (q & 1) ? (o - u) : (u + o);
        o = __shfl_xor(u, 2); u = (q & 2) ? (o - u) : (u + o);
        o = __shfl_xor(u, 4); u = (q & 4) ? (o - u) : (u + o);
        d += __shfl_xor(d, 1);
        d += __shfl_xor(d, 2);
        d += __shfl_xor(d, 4);
        // lane q=4: z0; q=2: z1; q=1: z2; q=0: z3 (=sum of d)

        if (c >= 0) {
            float z = (q == 0) ? d : u;
            out[img * 4 + c] = z;        // raw z, normalized by K2
            accz  += z;
            accz2 += z * z;
        }
    }

    // ---- per-block partials -> private slot (no global atomics, no memset)
    if (c >= 0) {
        atomicAdd(&spart[c], accz);
        atomicAdd(&spart[4 + c], accz2);
    }
    __syncthreads();
    if (t < 8) slots[blockIdx.x * 8 + t] = spart[t];
}

// ---------------------------------------------------------------- K2
// Reduce per-block slots + finalize BN stats + apply affine in place.
__global__ __launch_bounds__(256) void bn_apply(float* __restrict__ out,
                                                const float* __restrict__ slots,
                                                const float* __restrict__ gamma,
                                                const float* __restrict__ beta) {
    __shared__ float red[256];
    __shared__ float sc[8];
    const int t = threadIdx.x;
    const int ch = t & 7, g = t >> 3;      // g in 0..31
    float s = 0.0f;
#pragma unroll
    for (int k = 0; k < NBLK / 32; ++k)
        s += slots[(size_t)(g + 32 * k) * 8 + ch];
    red[t] = s;
    __syncthreads();
#pragma unroll
    for (int stp = 128; stp >= 8; stp >>= 1) {
        if (t < stp) red[t] += red[t + stp];
        __syncthreads();
    }
    if (t < 4) {
        float mu  = red[t] * (1.0f / BATCH);
        float var = red[4 + t] * (1.0f / BATCH) - mu * mu;
        float a = gamma[t] * rsqrtf(var + 1e-5f);
        sc[t]     = a;
        sc[4 + t] = beta[t] - mu * a;
    }
    __syncthreads();
    int i = blockIdx.x * 256 + t;   // one float4 (one image) each
    float4 z = ((float4*)out)[i];
    z.x = fmaf(z.x, sc[0], sc[4]);
    z.y = fmaf(z.y, sc[1], sc[5]);
    z.z = fmaf(z.z, sc[2], sc[6]);
    z.w = fmaf(z.w, sc[3], sc[7]);
    ((float4*)out)[i] = z;
}

extern "C" void kernel_launch(void* const* d_in, const int* in_sizes, int n_in,
                              void* d_out, int out_size, void* d_ws, size_t ws_size,
                              hipStream_t stream) {
    const float* x      = (const float*)d_in[0];
    const float* params = (const float*)d_in[1];
    const float* gamma  = (const float*)d_in[2];
    const float* beta   = (const float*)d_in[3];
    float* out = (float*)d_out;
    float* ws  = (float*)d_ws;

    hipLaunchKernelGGL(circuit_kernel, dim3(NBLK), dim3(256), 0, stream,
                       x, params, out, ws);
    hipLaunchKernelGGL(bn_apply, dim3(BATCH / 256), dim3(256), 0, stream,
                       out, ws, gamma, beta);
}